// Round 4
// baseline (624.167 us; speedup 1.0000x reference)
//
#include <hip/hip_runtime.h>
#include <hip/hip_bf16.h>
#include <type_traits>

typedef __bf16 bf16_t;
typedef __bf16 bf16x8 __attribute__((ext_vector_type(8)));
typedef float floatx4 __attribute__((ext_vector_type(4)));
typedef short v2s __attribute__((ext_vector_type(2)));

#define NN 50000
#define EE 800000
#define DD 128

// ---- ws layout (bytes) ----
// [0]   int flag_f32 (1 = floats are fp32, 0 = bf16)
// [4]   int flag_i64 (1 = edge_index is int64, 0 = int32)
// [256] transposed weights, always bf16:
#define W1T_OFF   256                                  // [128][288] (K padded 272->288, zero-filled)
#define W2T_OFF   (W1T_OFF + (size_t)128 * 288 * 2)    // [128][128]
#define NW1T_OFF  (W2T_OFF + (size_t)128 * 128 * 2)    // [128][256]
#define NW2T_OFF  (NW1T_OFF + (size_t)128 * 256 * 2)   // [128][128]

// LDS pitches (bf16 elements; multiples of 8 keep 16B alignment for b128 ops)
#define PA 304   // edge A-tile pitch (288 + 16 pad)
#define PB 48    // B chunk pitch (32 + 16 pad)
#define PN 272   // node A-tile pitch (256 + 16 pad)

// ---- dtype-detect: 1 thread, writes flags ----
__global__ void detect_kernel(const unsigned short* __restrict__ xraw,
                              const unsigned int* __restrict__ eiraw,
                              int* __restrict__ flags)
{
    // float width: even uint16s of x are bf16 normals (exp in [100,140] ~always)
    // if bf16; they are fp32 low-mantissa halves (~16% hit rate) if fp32.
    int cnt = 0;
    for (int i = 0; i < 64; ++i) {
        unsigned short u = xraw[2 * i];
        int ex = (u >> 7) & 0xFF;
        if (ex >= 100 && ex <= 140) cnt++;
    }
    flags[0] = (cnt < 32) ? 1 : 0;   // 1 => fp32
    // int width: odd uint32s are the zero high-words iff int64 (values < 50000)
    int zc = 0;
    for (int i = 0; i < 32; ++i)
        if (eiraw[2 * i + 1] == 0u) zc++;
    flags[1] = (zc >= 16) ? 1 : 0;   // 1 => int64
}

__device__ inline int load_idx(const void* ei, int i64, size_t pos)
{
    return i64 ? (int)((const long long*)ei)[pos] : ((const int*)ei)[pos];
}

// copy 32 contiguous elements FT -> bf16 LDS
template <typename FT>
__device__ inline void cp32(bf16_t* dst, const FT* src)
{
    if constexpr (std::is_same<FT, float>::value) {
#pragma unroll
        for (int i = 0; i < 32; i += 4) {
            float4 v = *(const float4*)(src + i);
            dst[i + 0] = (bf16_t)v.x; dst[i + 1] = (bf16_t)v.y;
            dst[i + 2] = (bf16_t)v.z; dst[i + 3] = (bf16_t)v.w;
        }
    } else {
#pragma unroll
        for (int i = 0; i < 32; i += 8)
            *(bf16x8*)(dst + i) = *(const bf16x8*)(src + i);
    }
}

template <typename FT>
__device__ inline void cp8(bf16_t* dst, const FT* src)
{
    if constexpr (std::is_same<FT, float>::value) {
#pragma unroll
        for (int i = 0; i < 8; i += 4) {
            float4 v = *(const float4*)(src + i);
            dst[i + 0] = (bf16_t)v.x; dst[i + 1] = (bf16_t)v.y;
            dst[i + 2] = (bf16_t)v.z; dst[i + 3] = (bf16_t)v.w;
        }
    } else {
        *(bf16x8*)dst = *(const bf16x8*)src;
    }
}

// ---- flag-gated zero of d_out (agg accumulator), FT decides byte count ----
template <typename FT>
__global__ __launch_bounds__(256) void zero_kernel(float4* __restrict__ out,
                                                   const int* __restrict__ flags)
{
    constexpr int WANT = std::is_same<FT, float>::value ? 1 : 0;
    if (flags[0] != WANT) return;
    const size_t n16 = (size_t)NN * DD * sizeof(FT) / 16;
    const float4 z = make_float4(0.f, 0.f, 0.f, 0.f);
    for (size_t i = (size_t)blockIdx.x * 256 + threadIdx.x; i < n16;
         i += (size_t)gridDim.x * 256)
        out[i] = z;
}

// ---- prep: transpose weights into ws as bf16 ----
template <typename FT>
__global__ __launch_bounds__(256) void prep_kernel(
    const FT* __restrict__ eW1, const FT* __restrict__ eW2,
    const FT* __restrict__ nW1, const FT* __restrict__ nW2,
    bf16_t* __restrict__ W1t, bf16_t* __restrict__ W2t,
    bf16_t* __restrict__ nW1t, bf16_t* __restrict__ nW2t,
    const int* __restrict__ flags)
{
    constexpr int WANT = std::is_same<FT, float>::value ? 1 : 0;
    if (flags[0] != WANT) return;
    int idx = blockIdx.x * 256 + threadIdx.x;
    if (idx < 128 * 288) {
        int n = idx / 288;
        int k = idx - n * 288;
        W1t[idx] = (k < 272) ? (bf16_t)(float)eW1[k * 128 + n] : (bf16_t)0.0f;
    } else if (idx < 128 * 288 + 128 * 128) {
        int j = idx - 128 * 288;
        int n = j >> 7, k = j & 127;
        W2t[j] = (bf16_t)(float)eW2[k * 128 + n];
    } else if (idx < 128 * 288 + 128 * 128 + 128 * 256) {
        int j = idx - (128 * 288 + 128 * 128);
        int n = j >> 8, k = j & 255;
        nW1t[j] = (bf16_t)(float)nW1[k * 128 + n];
    } else if (idx < 128 * 288 + 128 * 128 + 128 * 256 + 128 * 128) {
        int j = idx - (128 * 288 + 128 * 128 + 128 * 256);
        int n = j >> 7, k = j & 127;
        nW2t[j] = (bf16_t)(float)nW2[k * 128 + n];
    }
}

// ---- packed bf16x2 atomic add (global_atomic_pk_add_bf16 on gfx950) ----
__device__ inline void pk_atomic_add_bf16(bf16_t* addr, float lo, float hi)
{
#if __has_builtin(__builtin_amdgcn_global_atomic_fadd_v2bf16)
    union { bf16_t b[2]; v2s s; } pk;
    pk.b[0] = (bf16_t)lo;
    pk.b[1] = (bf16_t)hi;
    (void)__builtin_amdgcn_global_atomic_fadd_v2bf16((v2s*)addr, pk.s);
#else
    unsigned int* w = (unsigned int*)addr;
    unsigned int old = __hip_atomic_load(w, __ATOMIC_RELAXED, __HIP_MEMORY_SCOPE_AGENT);
    while (true) {
        union { unsigned int u; bf16_t b[2]; } cur;
        cur.u = old;
        cur.b[0] = (bf16_t)((float)cur.b[0] + lo);
        cur.b[1] = (bf16_t)((float)cur.b[1] + hi);
        unsigned int prev = atomicCAS(w, old, cur.u);
        if (prev == old) break;
        old = prev;
    }
#endif
}

// -------- edge MLP (two layers, silu) + atomic scatter-add into agg (= d_out) --------
// block = 256 thr (4 waves); tile = 64 edges x 128 feats; wave = 16 edges x 128 feats
template <typename FT>
__global__ __launch_bounds__(256) void edge_kernel(
    const FT* __restrict__ x, const void* __restrict__ ei,
    const FT* __restrict__ ea,
    const bf16_t* __restrict__ W1t, const FT* __restrict__ b1,
    const bf16_t* __restrict__ W2t, const FT* __restrict__ b2,
    void* __restrict__ aggv, const int* __restrict__ flags)
{
    constexpr int WANT = std::is_same<FT, float>::value ? 1 : 0;
    if (flags[0] != WANT) return;
    const int i64 = flags[1];

    __shared__ bf16_t sA[64 * PA];   // edge_input [64][288], cols 0..127 reused for h
    __shared__ bf16_t sB[128 * PB];  // W^T chunk [128 n][32 k]
    const int tid = threadIdx.x;
    const int e0 = blockIdx.x * 64;

    // ---- stage A: [x[row] | x[col] | edge_attr | 0-pad] ----
    {
        const int m = tid >> 2;      // edge row in tile
        const int part = tid & 3;    // 32-col slice of each 128 half
        const int e = e0 + m;
        int rn = load_idx(ei, i64, e);
        int cn = load_idx(ei, i64, (size_t)EE + e);
        rn = min(max(rn, 0), NN - 1);
        cn = min(max(cn, 0), NN - 1);
        cp32<FT>(&sA[m * PA + part * 32], x + (size_t)rn * DD + part * 32);
        cp32<FT>(&sA[m * PA + 128 + part * 32], x + (size_t)cn * DD + part * 32);
        if (part < 2) {
            cp8<FT>(&sA[m * PA + 256 + part * 8], ea + (size_t)e * 16 + part * 8);
        } else {
            *(float4*)&sA[m * PA + 256 + part * 8] = make_float4(0.f, 0.f, 0.f, 0.f);
        }
    }

    const int lane = tid & 63;
    const int wv = tid >> 6;
    const int ml = lane & 15;   // A row / B col / C col within 16-tile
    const int q = lane >> 4;    // quad: k = q*8+j for A/B, row = q*4+r for C/D
    const int m0 = wv * 16;

    const floatx4 fzero = {0.f, 0.f, 0.f, 0.f};
    floatx4 acc[8];
#pragma unroll
    for (int i = 0; i < 8; ++i) acc[i] = fzero;

    // ---- layer 1: [64x288] @ [288x128], 9 K-chunks of 32 ----
    for (int kc = 0; kc < 9; ++kc) {
        __syncthreads();
        {
            const int n = tid >> 1;
            const int half = tid & 1;
            const bf16x8* src = (const bf16x8*)(W1t + n * 288 + kc * 32 + half * 16);
            bf16x8* dst = (bf16x8*)&sB[n * PB + half * 16];
            dst[0] = src[0];
            dst[1] = src[1];
        }
        __syncthreads();
        const bf16x8 a = *(const bf16x8*)&sA[(m0 + ml) * PA + kc * 32 + q * 8];
#pragma unroll
        for (int nt = 0; nt < 8; ++nt) {
            const bf16x8 b = *(const bf16x8*)&sB[(nt * 16 + ml) * PB + q * 8];
            acc[nt] = __builtin_amdgcn_mfma_f32_16x16x32_bf16(a, b, acc[nt], 0, 0, 0);
        }
    }

    // ---- h = silu(acc + b1) -> sA[:, 0:128] ----
#pragma unroll
    for (int nt = 0; nt < 8; ++nt) {
        const float bias = (float)b1[nt * 16 + ml];
#pragma unroll
        for (int r = 0; r < 4; ++r) {
            float v = acc[nt][r] + bias;
            v = v / (1.f + __expf(-v));
            sA[(m0 + q * 4 + r) * PA + nt * 16 + ml] = (bf16_t)v;
        }
    }
    __syncthreads();

    floatx4 acc2[8];
#pragma unroll
    for (int i = 0; i < 8; ++i) acc2[i] = fzero;

    // ---- layer 2: [64x128] @ [128x128], 4 K-chunks ----
    for (int kc = 0; kc < 4; ++kc) {
        __syncthreads();
        {
            const int n = tid >> 1;
            const int half = tid & 1;
            const bf16x8* src = (const bf16x8*)(W2t + n * 128 + kc * 32 + half * 16);
            bf16x8* dst = (bf16x8*)&sB[n * PB + half * 16];
            dst[0] = src[0];
            dst[1] = src[1];
        }
        __syncthreads();
        const bf16x8 a = *(const bf16x8*)&sA[(m0 + ml) * PA + kc * 32 + q * 8];
#pragma unroll
        for (int nt = 0; nt < 8; ++nt) {
            const bf16x8 b = *(const bf16x8*)&sB[(nt * 16 + ml) * PB + q * 8];
            acc2[nt] = __builtin_amdgcn_mfma_f32_16x16x32_bf16(a, b, acc2[nt], 0, 0, 0);
        }
    }

    // ---- m_ij = silu(acc2 + b2); scatter-add into agg[row] ----
    float bias2[8];
#pragma unroll
    for (int nt = 0; nt < 8; ++nt) bias2[nt] = (float)b2[nt * 16 + ml];
#pragma unroll
    for (int r = 0; r < 4; ++r) {
        const int e = e0 + m0 + q * 4 + r;
        int rn = load_idx(ei, i64, e);
        rn = min(max(rn, 0), NN - 1);
#pragma unroll
        for (int nt = 0; nt < 8; ++nt) {
            float v = acc2[nt][r] + bias2[nt];
            v = v / (1.f + __expf(-v));
            if constexpr (std::is_same<FT, float>::value) {
                atomicAdd((float*)aggv + (size_t)rn * DD + nt * 16 + ml, v);
            } else {
                const float pv = __shfl_xor(v, 1, 64);
                if ((ml & 1) == 0)
                    pk_atomic_add_bf16((bf16_t*)aggv + (size_t)rn * DD + nt * 16 + ml, v, pv);
            }
        }
    }
}

// -------- node MLP: out = x + (silu([x|agg] @ nW1 + nb1) @ nW2 + nb2), in-place over agg --------
template <typename FT>
__global__ __launch_bounds__(256) void node_kernel(
    const FT* __restrict__ x,
    const bf16_t* __restrict__ nW1t, const FT* __restrict__ nb1,
    const bf16_t* __restrict__ nW2t, const FT* __restrict__ nb2,
    void* __restrict__ outv, const int* __restrict__ flags)
{
    constexpr int WANT = std::is_same<FT, float>::value ? 1 : 0;
    if (flags[0] != WANT) return;

    __shared__ bf16_t sA[64 * PN];
    __shared__ bf16_t sB[128 * PB];
    const int tid = threadIdx.x;
    const int n0 = blockIdx.x * 64;
    FT* out = (FT*)outv;

    // ---- stage A: [x | agg] (agg read from out; this block's own rows only) ----
    {
        const int m = tid >> 2;
        const int p = tid & 3;
        int n = n0 + m;
        if (n >= NN) n = NN - 1;  // clamp; stores guarded below
        const FT* srcbase = (p < 2) ? x : (const FT*)out;
        const int col = (p & 1) * 64;
        cp32<FT>(&sA[m * PN + (p >> 1) * 128 + col], srcbase + (size_t)n * DD + col);
        cp32<FT>(&sA[m * PN + (p >> 1) * 128 + col + 32], srcbase + (size_t)n * DD + col + 32);
    }

    const int lane = tid & 63;
    const int wv = tid >> 6;
    const int ml = lane & 15;
    const int q = lane >> 4;
    const int m0 = wv * 16;

    const floatx4 fzero = {0.f, 0.f, 0.f, 0.f};
    floatx4 acc[8];
#pragma unroll
    for (int i = 0; i < 8; ++i) acc[i] = fzero;

    // ---- layer 1: [64x256] @ [256x128], 8 K-chunks ----
    for (int kc = 0; kc < 8; ++kc) {
        __syncthreads();
        {
            const int n = tid >> 1;
            const int half = tid & 1;
            const bf16x8* src = (const bf16x8*)(nW1t + n * 256 + kc * 32 + half * 16);
            bf16x8* dst = (bf16x8*)&sB[n * PB + half * 16];
            dst[0] = src[0];
            dst[1] = src[1];
        }
        __syncthreads();
        const bf16x8 a = *(const bf16x8*)&sA[(m0 + ml) * PN + kc * 32 + q * 8];
#pragma unroll
        for (int nt = 0; nt < 8; ++nt) {
            const bf16x8 b = *(const bf16x8*)&sB[(nt * 16 + ml) * PB + q * 8];
            acc[nt] = __builtin_amdgcn_mfma_f32_16x16x32_bf16(a, b, acc[nt], 0, 0, 0);
        }
    }

    // ---- h = silu(acc + nb1) -> sA[:, 0:128] ----
#pragma unroll
    for (int nt = 0; nt < 8; ++nt) {
        const float bias = (float)nb1[nt * 16 + ml];
#pragma unroll
        for (int r = 0; r < 4; ++r) {
            float v = acc[nt][r] + bias;
            v = v / (1.f + __expf(-v));
            sA[(m0 + q * 4 + r) * PN + nt * 16 + ml] = (bf16_t)v;
        }
    }
    __syncthreads();

    floatx4 acc2[8];
#pragma unroll
    for (int i = 0; i < 8; ++i) acc2[i] = fzero;

    // ---- layer 2: [64x128] @ [128x128], 4 K-chunks (NO silu) ----
    for (int kc = 0; kc < 4; ++kc) {
        __syncthreads();
        {
            const int n = tid >> 1;
            const int half = tid & 1;
            const bf16x8* src = (const bf16x8*)(nW2t + n * 128 + kc * 32 + half * 16);
            bf16x8* dst = (bf16x8*)&sB[n * PB + half * 16];
            dst[0] = src[0];
            dst[1] = src[1];
        }
        __syncthreads();
        const bf16x8 a = *(const bf16x8*)&sA[(m0 + ml) * PN + kc * 32 + q * 8];
#pragma unroll
        for (int nt = 0; nt < 8; ++nt) {
            const bf16x8 b = *(const bf16x8*)&sB[(nt * 16 + ml) * PB + q * 8];
            acc2[nt] = __builtin_amdgcn_mfma_f32_16x16x32_bf16(a, b, acc2[nt], 0, 0, 0);
        }
    }

    // ---- out = x + (acc2 + nb2)  (in-place over this block's agg rows) ----
    float bias2[8];
#pragma unroll
    for (int nt = 0; nt < 8; ++nt) bias2[nt] = (float)nb2[nt * 16 + ml];
#pragma unroll
    for (int r = 0; r < 4; ++r) {
        const int n = n0 + m0 + q * 4 + r;
        if (n < NN) {
#pragma unroll
            for (int nt = 0; nt < 8; ++nt) {
                const int col = nt * 16 + ml;
                float v = acc2[nt][r] + bias2[nt];
                float xv = (float)x[(size_t)n * DD + col];
                out[(size_t)n * DD + col] = (FT)(xv + v);
            }
        }
    }
}

extern "C" void kernel_launch(void* const* d_in, const int* in_sizes, int n_in,
                              void* d_out, int out_size, void* d_ws, size_t ws_size,
                              hipStream_t stream)
{
    const void* x   = d_in[0];
    const void* ei  = d_in[1];
    const void* ea  = d_in[2];
    const void* eW1 = d_in[3];
    const void* eb1 = d_in[4];
    const void* eW2 = d_in[5];
    const void* eb2 = d_in[6];
    const void* nW1 = d_in[7];
    const void* nb1 = d_in[8];
    const void* nW2 = d_in[9];
    const void* nb2 = d_in[10];

    char* ws = (char*)d_ws;
    int*    flags = (int*)ws;
    bf16_t* W1t   = (bf16_t*)(ws + W1T_OFF);
    bf16_t* W2t   = (bf16_t*)(ws + W2T_OFF);
    bf16_t* nW1t  = (bf16_t*)(ws + NW1T_OFF);
    bf16_t* nW2t  = (bf16_t*)(ws + NW2T_OFF);

    detect_kernel<<<1, 1, 0, stream>>>((const unsigned short*)x,
                                       (const unsigned int*)ei, flags);

    zero_kernel<bf16_t><<<6250, 256, 0, stream>>>((float4*)d_out, flags);
    zero_kernel<float><<<6250, 256, 0, stream>>>((float4*)d_out, flags);

    prep_kernel<bf16_t><<<400, 256, 0, stream>>>(
        (const bf16_t*)eW1, (const bf16_t*)eW2, (const bf16_t*)nW1, (const bf16_t*)nW2,
        W1t, W2t, nW1t, nW2t, flags);
    prep_kernel<float><<<400, 256, 0, stream>>>(
        (const float*)eW1, (const float*)eW2, (const float*)nW1, (const float*)nW2,
        W1t, W2t, nW1t, nW2t, flags);

    edge_kernel<bf16_t><<<EE / 64, 256, 0, stream>>>(
        (const bf16_t*)x, ei, (const bf16_t*)ea, W1t, (const bf16_t*)eb1,
        W2t, (const bf16_t*)eb2, d_out, flags);
    edge_kernel<float><<<EE / 64, 256, 0, stream>>>(
        (const float*)x, ei, (const float*)ea, W1t, (const float*)eb1,
        W2t, (const float*)eb2, d_out, flags);

    node_kernel<bf16_t><<<(NN + 63) / 64, 256, 0, stream>>>(
        (const bf16_t*)x, nW1t, (const bf16_t*)nb1, nW2t, (const bf16_t*)nb2,
        d_out, flags);
    node_kernel<float><<<(NN + 63) / 64, 256, 0, stream>>>(
        (const float*)x, nW1t, (const float*)nb1, nW2t, (const float*)nb2,
        d_out, flags);
}

// Round 5
// 604.850 us; speedup vs baseline: 1.0319x; 1.0319x over previous
//
#include <hip/hip_runtime.h>
#include <hip/hip_bf16.h>
#include <type_traits>

typedef __bf16 bf16_t;
typedef __bf16 bf16x8 __attribute__((ext_vector_type(8)));
typedef float floatx4 __attribute__((ext_vector_type(4)));
typedef short v2s __attribute__((ext_vector_type(2)));

#define NN 50000
#define EE 800000
#define DD 128

// ---- ws layout (bytes) ----
// [0]      int flag_f32 (1 = floats are fp32), int flag_i64 (1 = edge_index int64)
// [256]    transposed weights (bf16)
#define W1T_OFF   256                                  // [128][288] (K 272->288 zero-pad)
#define W2T_OFF   (W1T_OFF + (size_t)128 * 288 * 2)    // [128][128]
#define NW1T_OFF  (W2T_OFF + (size_t)128 * 128 * 2)    // [128][256]
#define NW2T_OFF  (NW1T_OFF + (size_t)128 * 256 * 2)   // [128][128]
#define BIASF_OFF (NW2T_OFF + (size_t)128 * 128 * 2)   // float[512]: b1|b2|nb1|nb2
#define XB_OFF    207360                               // bf16 x copy [NN][DD], 256B aligned
#define AGG_OFF   (XB_OFF + (size_t)NN * DD * 2)       // bf16 agg [NN][DD]
#define AGG_BYTES ((size_t)NN * DD * 2)
#define WS_NEED   (AGG_OFF + AGG_BYTES)                // 25,807,360 B

// LDS pitches (bf16 elems; multiples of 8 keep 16B alignment)
#define PA 304   // edge A-tile pitch (288 + 16 pad)
#define PB 48    // B chunk pitch (32 + 16 pad)
#define PN 272   // node A-tile pitch (256 + 16 pad)

// ---- dtype-detect: 1 thread, writes flags ----
__global__ void detect_kernel(const unsigned short* __restrict__ xraw,
                              const unsigned int* __restrict__ eiraw,
                              int* __restrict__ flags)
{
    int cnt = 0;
    for (int i = 0; i < 64; ++i) {
        unsigned short u = xraw[2 * i];
        int ex = (u >> 7) & 0xFF;
        if (ex >= 100 && ex <= 140) cnt++;
    }
    flags[0] = (cnt < 32) ? 1 : 0;   // 1 => fp32
    int zc = 0;
    for (int i = 0; i < 32; ++i)
        if (eiraw[2 * i + 1] == 0u) zc++;
    flags[1] = (zc >= 16) ? 1 : 0;   // 1 => int64
}

__device__ inline int load_idx(const void* ei, int i64, size_t pos)
{
    return i64 ? (int)((const long long*)ei)[pos] : ((const int*)ei)[pos];
}

// copy 32 contiguous elements FT -> bf16 LDS
template <typename FT>
__device__ inline void cp32(bf16_t* dst, const FT* src)
{
    if constexpr (std::is_same<FT, float>::value) {
#pragma unroll
        for (int i = 0; i < 32; i += 4) {
            float4 v = *(const float4*)(src + i);
            dst[i + 0] = (bf16_t)v.x; dst[i + 1] = (bf16_t)v.y;
            dst[i + 2] = (bf16_t)v.z; dst[i + 3] = (bf16_t)v.w;
        }
    } else {
#pragma unroll
        for (int i = 0; i < 32; i += 8)
            *(bf16x8*)(dst + i) = *(const bf16x8*)(src + i);
    }
}

template <typename FT>
__device__ inline void cp8(bf16_t* dst, const FT* src)
{
    if constexpr (std::is_same<FT, float>::value) {
#pragma unroll
        for (int i = 0; i < 8; i += 4) {
            float4 v = *(const float4*)(src + i);
            dst[i + 0] = (bf16_t)v.x; dst[i + 1] = (bf16_t)v.y;
            dst[i + 2] = (bf16_t)v.z; dst[i + 3] = (bf16_t)v.w;
        }
    } else {
        *(bf16x8*)dst = *(const bf16x8*)src;
    }
}

// ---- packed bf16x2 atomic add (global_atomic_pk_add_bf16 on gfx950) ----
__device__ inline void pk_atomic_add_bf16(bf16_t* addr, float lo, float hi)
{
#if __has_builtin(__builtin_amdgcn_global_atomic_fadd_v2bf16)
    union { bf16_t b[2]; v2s s; } pk;
    pk.b[0] = (bf16_t)lo;
    pk.b[1] = (bf16_t)hi;
    (void)__builtin_amdgcn_global_atomic_fadd_v2bf16((v2s*)addr, pk.s);
#else
    unsigned int* w = (unsigned int*)addr;
    unsigned int old = __hip_atomic_load(w, __ATOMIC_RELAXED, __HIP_MEMORY_SCOPE_AGENT);
    while (true) {
        union { unsigned int u; bf16_t b[2]; } cur;
        cur.u = old;
        cur.b[0] = (bf16_t)((float)cur.b[0] + lo);
        cur.b[1] = (bf16_t)((float)cur.b[1] + hi);
        unsigned int prev = atomicCAS(w, old, cur.u);
        if (prev == old) break;
        old = prev;
    }
#endif
}

// ---- prep: transpose weights -> bf16 ws; upconvert biases -> float ws ----
template <typename FT>
__global__ __launch_bounds__(256) void prep_kernel(
    const FT* __restrict__ eW1, const FT* __restrict__ eW2,
    const FT* __restrict__ nW1, const FT* __restrict__ nW2,
    const FT* __restrict__ b1, const FT* __restrict__ b2,
    const FT* __restrict__ nb1, const FT* __restrict__ nb2,
    bf16_t* __restrict__ W1t, bf16_t* __restrict__ W2t,
    bf16_t* __restrict__ nW1t, bf16_t* __restrict__ nW2t,
    float* __restrict__ biasF, const int* __restrict__ flags)
{
    constexpr int WANT = std::is_same<FT, float>::value ? 1 : 0;
    if (flags[0] != WANT) return;
    int idx = blockIdx.x * 256 + threadIdx.x;
    if (idx < 128 * 288) {
        int n = idx / 288;
        int k = idx - n * 288;
        W1t[idx] = (k < 272) ? (bf16_t)(float)eW1[k * 128 + n] : (bf16_t)0.0f;
    } else if (idx < 128 * 288 + 128 * 128) {
        int j = idx - 128 * 288;
        int n = j >> 7, k = j & 127;
        W2t[j] = (bf16_t)(float)eW2[k * 128 + n];
    } else if (idx < 128 * 288 + 128 * 128 + 128 * 256) {
        int j = idx - (128 * 288 + 128 * 128);
        int n = j >> 8, k = j & 255;
        nW1t[j] = (bf16_t)(float)nW1[k * 128 + n];
    } else if (idx < 102400) {
        int j = idx - (128 * 288 + 128 * 128 + 128 * 256);
        int n = j >> 7, k = j & 127;
        nW2t[j] = (bf16_t)(float)nW2[k * 128 + n];
    } else if (idx < 102912) {
        int j = idx - 102400;       // 0..511
        int which = j >> 7, c = j & 127;
        const FT* src = which == 0 ? b1 : which == 1 ? b2 : which == 2 ? nb1 : nb2;
        biasF[j] = (float)src[c];
    }
}

// ---- conv_x: x (FT) -> xb (bf16), 8 elems/thread ----
template <typename FT>
__global__ __launch_bounds__(256) void conv_x_kernel(
    const FT* __restrict__ x, bf16_t* __restrict__ xb,
    const int* __restrict__ flags)
{
    constexpr int WANT = std::is_same<FT, float>::value ? 1 : 0;
    if (flags[0] != WANT) return;
    size_t i = ((size_t)blockIdx.x * 256 + threadIdx.x) * 8;
    if (i >= (size_t)NN * DD) return;
    bf16x8 v;
    if constexpr (std::is_same<FT, float>::value) {
        float4 a = *(const float4*)(x + i);
        float4 b = *(const float4*)(x + i + 4);
        v[0] = (bf16_t)a.x; v[1] = (bf16_t)a.y; v[2] = (bf16_t)a.z; v[3] = (bf16_t)a.w;
        v[4] = (bf16_t)b.x; v[5] = (bf16_t)b.y; v[6] = (bf16_t)b.z; v[7] = (bf16_t)b.w;
    } else {
        v = *(const bf16x8*)(x + i);
    }
    *(bf16x8*)(xb + i) = v;
}

// ======== NEW PATH: edge MLP + pk-bf16 scatter into agg (ws) — dtype-free ========
__global__ __launch_bounds__(256) void edge_kernel_v2(
    const bf16_t* __restrict__ xb, const void* __restrict__ ei,
    const void* __restrict__ ea,
    const bf16_t* __restrict__ W1t, const bf16_t* __restrict__ W2t,
    const float* __restrict__ biasF,
    bf16_t* __restrict__ agg, const int* __restrict__ flags)
{
    const int f32 = flags[0];
    const int i64 = flags[1];

    __shared__ bf16_t sA[64 * PA];
    __shared__ bf16_t sB[128 * PB];
    const int tid = threadIdx.x;
    const int e0 = blockIdx.x * 64;

    // ---- stage A: [xb[row] | xb[col] | edge_attr | 0-pad] ----
    {
        const int m = tid >> 2;
        const int part = tid & 3;
        const int e = e0 + m;
        int rn = load_idx(ei, i64, e);
        int cn = load_idx(ei, i64, (size_t)EE + e);
        rn = min(max(rn, 0), NN - 1);
        cn = min(max(cn, 0), NN - 1);
        // 32 bf16 from each endpoint row (4 x 16B)
        const bf16x8* xr = (const bf16x8*)(xb + (size_t)rn * DD + part * 32);
        const bf16x8* xc = (const bf16x8*)(xb + (size_t)cn * DD + part * 32);
        bf16x8* dR = (bf16x8*)&sA[m * PA + part * 32];
        bf16x8* dC = (bf16x8*)&sA[m * PA + 128 + part * 32];
#pragma unroll
        for (int i = 0; i < 4; ++i) dR[i] = xr[i];
#pragma unroll
        for (int i = 0; i < 4; ++i) dC[i] = xc[i];
        if (part < 2) {
            if (f32) cp8<float>(&sA[m * PA + 256 + part * 8], (const float*)ea + (size_t)e * 16 + part * 8);
            else     cp8<bf16_t>(&sA[m * PA + 256 + part * 8], (const bf16_t*)ea + (size_t)e * 16 + part * 8);
        } else {
            *(float4*)&sA[m * PA + 256 + part * 8] = make_float4(0.f, 0.f, 0.f, 0.f);
        }
    }

    const int lane = tid & 63;
    const int wv = tid >> 6;
    const int ml = lane & 15;
    const int q = lane >> 4;
    const int m0 = wv * 16;

    const floatx4 fzero = {0.f, 0.f, 0.f, 0.f};
    floatx4 acc[8];
#pragma unroll
    for (int i = 0; i < 8; ++i) acc[i] = fzero;

    // ---- layer 1: [64x288] @ [288x128], 9 K-chunks ----
    for (int kc = 0; kc < 9; ++kc) {
        __syncthreads();
        {
            const int n = tid >> 1;
            const int half = tid & 1;
            const bf16x8* src = (const bf16x8*)(W1t + n * 288 + kc * 32 + half * 16);
            bf16x8* dst = (bf16x8*)&sB[n * PB + half * 16];
            dst[0] = src[0];
            dst[1] = src[1];
        }
        __syncthreads();
        const bf16x8 a = *(const bf16x8*)&sA[(m0 + ml) * PA + kc * 32 + q * 8];
#pragma unroll
        for (int nt = 0; nt < 8; ++nt) {
            const bf16x8 b = *(const bf16x8*)&sB[(nt * 16 + ml) * PB + q * 8];
            acc[nt] = __builtin_amdgcn_mfma_f32_16x16x32_bf16(a, b, acc[nt], 0, 0, 0);
        }
    }

    // ---- h = silu(acc + b1) -> sA[:, 0:128] ----
#pragma unroll
    for (int nt = 0; nt < 8; ++nt) {
        const float bias = biasF[nt * 16 + ml];
#pragma unroll
        for (int r = 0; r < 4; ++r) {
            float v = acc[nt][r] + bias;
            v = v / (1.f + __expf(-v));
            sA[(m0 + q * 4 + r) * PA + nt * 16 + ml] = (bf16_t)v;
        }
    }
    __syncthreads();

    floatx4 acc2[8];
#pragma unroll
    for (int i = 0; i < 8; ++i) acc2[i] = fzero;

    // ---- layer 2: [64x128] @ [128x128], 4 K-chunks ----
    for (int kc = 0; kc < 4; ++kc) {
        __syncthreads();
        {
            const int n = tid >> 1;
            const int half = tid & 1;
            const bf16x8* src = (const bf16x8*)(W2t + n * 128 + kc * 32 + half * 16);
            bf16x8* dst = (bf16x8*)&sB[n * PB + half * 16];
            dst[0] = src[0];
            dst[1] = src[1];
        }
        __syncthreads();
        const bf16x8 a = *(const bf16x8*)&sA[(m0 + ml) * PA + kc * 32 + q * 8];
#pragma unroll
        for (int nt = 0; nt < 8; ++nt) {
            const bf16x8 b = *(const bf16x8*)&sB[(nt * 16 + ml) * PB + q * 8];
            acc2[nt] = __builtin_amdgcn_mfma_f32_16x16x32_bf16(a, b, acc2[nt], 0, 0, 0);
        }
    }

    // ---- m_ij = silu(acc2 + b2); pk-bf16 scatter-add ----
    float bias2[8];
#pragma unroll
    for (int nt = 0; nt < 8; ++nt) bias2[nt] = biasF[128 + nt * 16 + ml];
#pragma unroll
    for (int r = 0; r < 4; ++r) {
        const int e = e0 + m0 + q * 4 + r;
        int rn = load_idx(ei, i64, e);
        rn = min(max(rn, 0), NN - 1);
#pragma unroll
        for (int nt = 0; nt < 8; ++nt) {
            float v = acc2[nt][r] + bias2[nt];
            v = v / (1.f + __expf(-v));
            const float pv = __shfl_xor(v, 1, 64);
            if ((ml & 1) == 0)
                pk_atomic_add_bf16(agg + (size_t)rn * DD + nt * 16 + ml, v, pv);
        }
    }
}

// ======== NEW PATH: node MLP, agg from ws (bf16), out = x + update (FT) ========
template <typename FT>
__global__ __launch_bounds__(256) void node_kernel_v2(
    const FT* __restrict__ x, const bf16_t* __restrict__ xb,
    const bf16_t* __restrict__ agg,
    const bf16_t* __restrict__ nW1t, const bf16_t* __restrict__ nW2t,
    const float* __restrict__ biasF,
    FT* __restrict__ out, const int* __restrict__ flags)
{
    constexpr int WANT = std::is_same<FT, float>::value ? 1 : 0;
    if (flags[0] != WANT) return;

    __shared__ bf16_t sA[64 * PN];
    __shared__ bf16_t sB[128 * PB];
    const int tid = threadIdx.x;
    const int n0 = blockIdx.x * 64;

    // ---- stage A: [xb | agg], both bf16 coalesced ----
    {
        const int m = tid >> 2;
        const int p = tid & 3;
        int n = n0 + m;
        if (n >= NN) n = NN - 1;
        const bf16_t* srcbase = (p < 2) ? xb : agg;
        const int col = (p & 1) * 64;
        const bf16x8* src = (const bf16x8*)(srcbase + (size_t)n * DD + col);
        bf16x8* dst = (bf16x8*)&sA[m * PN + (p >> 1) * 128 + col];
#pragma unroll
        for (int i = 0; i < 8; ++i) dst[i] = src[i];
    }

    const int lane = tid & 63;
    const int wv = tid >> 6;
    const int ml = lane & 15;
    const int q = lane >> 4;
    const int m0 = wv * 16;

    const floatx4 fzero = {0.f, 0.f, 0.f, 0.f};
    floatx4 acc[8];
#pragma unroll
    for (int i = 0; i < 8; ++i) acc[i] = fzero;

    // ---- layer 1: [64x256] @ [256x128] ----
    for (int kc = 0; kc < 8; ++kc) {
        __syncthreads();
        {
            const int n = tid >> 1;
            const int half = tid & 1;
            const bf16x8* src = (const bf16x8*)(nW1t + n * 256 + kc * 32 + half * 16);
            bf16x8* dst = (bf16x8*)&sB[n * PB + half * 16];
            dst[0] = src[0];
            dst[1] = src[1];
        }
        __syncthreads();
        const bf16x8 a = *(const bf16x8*)&sA[(m0 + ml) * PN + kc * 32 + q * 8];
#pragma unroll
        for (int nt = 0; nt < 8; ++nt) {
            const bf16x8 b = *(const bf16x8*)&sB[(nt * 16 + ml) * PB + q * 8];
            acc[nt] = __builtin_amdgcn_mfma_f32_16x16x32_bf16(a, b, acc[nt], 0, 0, 0);
        }
    }

    // ---- h = silu(acc + nb1) -> sA[:, 0:128] ----
#pragma unroll
    for (int nt = 0; nt < 8; ++nt) {
        const float bias = biasF[256 + nt * 16 + ml];
#pragma unroll
        for (int r = 0; r < 4; ++r) {
            float v = acc[nt][r] + bias;
            v = v / (1.f + __expf(-v));
            sA[(m0 + q * 4 + r) * PN + nt * 16 + ml] = (bf16_t)v;
        }
    }
    __syncthreads();

    floatx4 acc2[8];
#pragma unroll
    for (int i = 0; i < 8; ++i) acc2[i] = fzero;

    // ---- layer 2: [64x128] @ [128x128] (no silu) ----
    for (int kc = 0; kc < 4; ++kc) {
        __syncthreads();
        {
            const int n = tid >> 1;
            const int half = tid & 1;
            const bf16x8* src = (const bf16x8*)(nW2t + n * 128 + kc * 32 + half * 16);
            bf16x8* dst = (bf16x8*)&sB[n * PB + half * 16];
            dst[0] = src[0];
            dst[1] = src[1];
        }
        __syncthreads();
        const bf16x8 a = *(const bf16x8*)&sA[(m0 + ml) * PN + kc * 32 + q * 8];
#pragma unroll
        for (int nt = 0; nt < 8; ++nt) {
            const bf16x8 b = *(const bf16x8*)&sB[(nt * 16 + ml) * PB + q * 8];
            acc2[nt] = __builtin_amdgcn_mfma_f32_16x16x32_bf16(a, b, acc2[nt], 0, 0, 0);
        }
    }

    // ---- out = x + (acc2 + nb2) ----
#pragma unroll
    for (int r = 0; r < 4; ++r) {
        const int n = n0 + m0 + q * 4 + r;
        if (n < NN) {
#pragma unroll
            for (int nt = 0; nt < 8; ++nt) {
                const int col = nt * 16 + ml;
                float v = acc2[nt][r] + biasF[384 + col];
                float xv = (float)x[(size_t)n * DD + col];
                out[(size_t)n * DD + col] = (FT)(xv + v);
            }
        }
    }
}

// ======== LEGACY PATH (ws too small): round-4 structure, agg in d_out ========
template <typename FT>
__global__ __launch_bounds__(256) void zero_kernel(float4* __restrict__ out,
                                                   const int* __restrict__ flags)
{
    constexpr int WANT = std::is_same<FT, float>::value ? 1 : 0;
    if (flags[0] != WANT) return;
    const size_t n16 = (size_t)NN * DD * sizeof(FT) / 16;
    const float4 z = make_float4(0.f, 0.f, 0.f, 0.f);
    for (size_t i = (size_t)blockIdx.x * 256 + threadIdx.x; i < n16;
         i += (size_t)gridDim.x * 256)
        out[i] = z;
}

template <typename FT>
__global__ __launch_bounds__(256) void edge_kernel_legacy(
    const FT* __restrict__ x, const void* __restrict__ ei,
    const FT* __restrict__ ea,
    const bf16_t* __restrict__ W1t, const FT* __restrict__ b1,
    const bf16_t* __restrict__ W2t, const FT* __restrict__ b2,
    void* __restrict__ aggv, const int* __restrict__ flags)
{
    constexpr int WANT = std::is_same<FT, float>::value ? 1 : 0;
    if (flags[0] != WANT) return;
    const int i64 = flags[1];

    __shared__ bf16_t sA[64 * PA];
    __shared__ bf16_t sB[128 * PB];
    const int tid = threadIdx.x;
    const int e0 = blockIdx.x * 64;

    {
        const int m = tid >> 2;
        const int part = tid & 3;
        const int e = e0 + m;
        int rn = load_idx(ei, i64, e);
        int cn = load_idx(ei, i64, (size_t)EE + e);
        rn = min(max(rn, 0), NN - 1);
        cn = min(max(cn, 0), NN - 1);
        cp32<FT>(&sA[m * PA + part * 32], x + (size_t)rn * DD + part * 32);
        cp32<FT>(&sA[m * PA + 128 + part * 32], x + (size_t)cn * DD + part * 32);
        if (part < 2) {
            cp8<FT>(&sA[m * PA + 256 + part * 8], ea + (size_t)e * 16 + part * 8);
        } else {
            *(float4*)&sA[m * PA + 256 + part * 8] = make_float4(0.f, 0.f, 0.f, 0.f);
        }
    }

    const int lane = tid & 63;
    const int wv = tid >> 6;
    const int ml = lane & 15;
    const int q = lane >> 4;
    const int m0 = wv * 16;

    const floatx4 fzero = {0.f, 0.f, 0.f, 0.f};
    floatx4 acc[8];
#pragma unroll
    for (int i = 0; i < 8; ++i) acc[i] = fzero;

    for (int kc = 0; kc < 9; ++kc) {
        __syncthreads();
        {
            const int n = tid >> 1;
            const int half = tid & 1;
            const bf16x8* src = (const bf16x8*)(W1t + n * 288 + kc * 32 + half * 16);
            bf16x8* dst = (bf16x8*)&sB[n * PB + half * 16];
            dst[0] = src[0];
            dst[1] = src[1];
        }
        __syncthreads();
        const bf16x8 a = *(const bf16x8*)&sA[(m0 + ml) * PA + kc * 32 + q * 8];
#pragma unroll
        for (int nt = 0; nt < 8; ++nt) {
            const bf16x8 b = *(const bf16x8*)&sB[(nt * 16 + ml) * PB + q * 8];
            acc[nt] = __builtin_amdgcn_mfma_f32_16x16x32_bf16(a, b, acc[nt], 0, 0, 0);
        }
    }

#pragma unroll
    for (int nt = 0; nt < 8; ++nt) {
        const float bias = (float)b1[nt * 16 + ml];
#pragma unroll
        for (int r = 0; r < 4; ++r) {
            float v = acc[nt][r] + bias;
            v = v / (1.f + __expf(-v));
            sA[(m0 + q * 4 + r) * PA + nt * 16 + ml] = (bf16_t)v;
        }
    }
    __syncthreads();

    floatx4 acc2[8];
#pragma unroll
    for (int i = 0; i < 8; ++i) acc2[i] = fzero;

    for (int kc = 0; kc < 4; ++kc) {
        __syncthreads();
        {
            const int n = tid >> 1;
            const int half = tid & 1;
            const bf16x8* src = (const bf16x8*)(W2t + n * 128 + kc * 32 + half * 16);
            bf16x8* dst = (bf16x8*)&sB[n * PB + half * 16];
            dst[0] = src[0];
            dst[1] = src[1];
        }
        __syncthreads();
        const bf16x8 a = *(const bf16x8*)&sA[(m0 + ml) * PA + kc * 32 + q * 8];
#pragma unroll
        for (int nt = 0; nt < 8; ++nt) {
            const bf16x8 b = *(const bf16x8*)&sB[(nt * 16 + ml) * PB + q * 8];
            acc2[nt] = __builtin_amdgcn_mfma_f32_16x16x32_bf16(a, b, acc2[nt], 0, 0, 0);
        }
    }

    float bias2[8];
#pragma unroll
    for (int nt = 0; nt < 8; ++nt) bias2[nt] = (float)b2[nt * 16 + ml];
#pragma unroll
    for (int r = 0; r < 4; ++r) {
        const int e = e0 + m0 + q * 4 + r;
        int rn = load_idx(ei, i64, e);
        rn = min(max(rn, 0), NN - 1);
#pragma unroll
        for (int nt = 0; nt < 8; ++nt) {
            float v = acc2[nt][r] + bias2[nt];
            v = v / (1.f + __expf(-v));
            if constexpr (std::is_same<FT, float>::value) {
                atomicAdd((float*)aggv + (size_t)rn * DD + nt * 16 + ml, v);
            } else {
                const float pv = __shfl_xor(v, 1, 64);
                if ((ml & 1) == 0)
                    pk_atomic_add_bf16((bf16_t*)aggv + (size_t)rn * DD + nt * 16 + ml, v, pv);
            }
        }
    }
}

template <typename FT>
__global__ __launch_bounds__(256) void node_kernel_legacy(
    const FT* __restrict__ x,
    const bf16_t* __restrict__ nW1t, const FT* __restrict__ nb1,
    const bf16_t* __restrict__ nW2t, const FT* __restrict__ nb2,
    void* __restrict__ outv, const int* __restrict__ flags)
{
    constexpr int WANT = std::is_same<FT, float>::value ? 1 : 0;
    if (flags[0] != WANT) return;

    __shared__ bf16_t sA[64 * PN];
    __shared__ bf16_t sB[128 * PB];
    const int tid = threadIdx.x;
    const int n0 = blockIdx.x * 64;
    FT* out = (FT*)outv;

    {
        const int m = tid >> 2;
        const int p = tid & 3;
        int n = n0 + m;
        if (n >= NN) n = NN - 1;
        const FT* srcbase = (p < 2) ? x : (const FT*)out;
        const int col = (p & 1) * 64;
        cp32<FT>(&sA[m * PN + (p >> 1) * 128 + col], srcbase + (size_t)n * DD + col);
        cp32<FT>(&sA[m * PN + (p >> 1) * 128 + col + 32], srcbase + (size_t)n * DD + col + 32);
    }

    const int lane = tid & 63;
    const int wv = tid >> 6;
    const int ml = lane & 15;
    const int q = lane >> 4;
    const int m0 = wv * 16;

    const floatx4 fzero = {0.f, 0.f, 0.f, 0.f};
    floatx4 acc[8];
#pragma unroll
    for (int i = 0; i < 8; ++i) acc[i] = fzero;

    for (int kc = 0; kc < 8; ++kc) {
        __syncthreads();
        {
            const int n = tid >> 1;
            const int half = tid & 1;
            const bf16x8* src = (const bf16x8*)(nW1t + n * 256 + kc * 32 + half * 16);
            bf16x8* dst = (bf16x8*)&sB[n * PB + half * 16];
            dst[0] = src[0];
            dst[1] = src[1];
        }
        __syncthreads();
        const bf16x8 a = *(const bf16x8*)&sA[(m0 + ml) * PN + kc * 32 + q * 8];
#pragma unroll
        for (int nt = 0; nt < 8; ++nt) {
            const bf16x8 b = *(const bf16x8*)&sB[(nt * 16 + ml) * PB + q * 8];
            acc[nt] = __builtin_amdgcn_mfma_f32_16x16x32_bf16(a, b, acc[nt], 0, 0, 0);
        }
    }

#pragma unroll
    for (int nt = 0; nt < 8; ++nt) {
        const float bias = (float)nb1[nt * 16 + ml];
#pragma unroll
        for (int r = 0; r < 4; ++r) {
            float v = acc[nt][r] + bias;
            v = v / (1.f + __expf(-v));
            sA[(m0 + q * 4 + r) * PN + nt * 16 + ml] = (bf16_t)v;
        }
    }
    __syncthreads();

    floatx4 acc2[8];
#pragma unroll
    for (int i = 0; i < 8; ++i) acc2[i] = fzero;

    for (int kc = 0; kc < 4; ++kc) {
        __syncthreads();
        {
            const int n = tid >> 1;
            const int half = tid & 1;
            const bf16x8* src = (const bf16x8*)(nW2t + n * 128 + kc * 32 + half * 16);
            bf16x8* dst = (bf16x8*)&sB[n * PB + half * 16];
            dst[0] = src[0];
            dst[1] = src[1];
        }
        __syncthreads();
        const bf16x8 a = *(const bf16x8*)&sA[(m0 + ml) * PN + kc * 32 + q * 8];
#pragma unroll
        for (int nt = 0; nt < 8; ++nt) {
            const bf16x8 b = *(const bf16x8*)&sB[(nt * 16 + ml) * PB + q * 8];
            acc2[nt] = __builtin_amdgcn_mfma_f32_16x16x32_bf16(a, b, acc2[nt], 0, 0, 0);
        }
    }

    float bias2[8];
#pragma unroll
    for (int nt = 0; nt < 8; ++nt) bias2[nt] = (float)nb2[nt * 16 + ml];
#pragma unroll
    for (int r = 0; r < 4; ++r) {
        const int n = n0 + m0 + q * 4 + r;
        if (n < NN) {
#pragma unroll
            for (int nt = 0; nt < 8; ++nt) {
                const int col = nt * 16 + ml;
                float v = acc2[nt][r] + bias2[nt];
                float xv = (float)x[(size_t)n * DD + col];
                out[(size_t)n * DD + col] = (FT)(xv + v);
            }
        }
    }
}

extern "C" void kernel_launch(void* const* d_in, const int* in_sizes, int n_in,
                              void* d_out, int out_size, void* d_ws, size_t ws_size,
                              hipStream_t stream)
{
    const void* x   = d_in[0];
    const void* ei  = d_in[1];
    const void* ea  = d_in[2];
    const void* eW1 = d_in[3];
    const void* eb1 = d_in[4];
    const void* eW2 = d_in[5];
    const void* eb2 = d_in[6];
    const void* nW1 = d_in[7];
    const void* nb1 = d_in[8];
    const void* nW2 = d_in[9];
    const void* nb2 = d_in[10];

    char* ws = (char*)d_ws;
    int*    flags = (int*)ws;
    bf16_t* W1t   = (bf16_t*)(ws + W1T_OFF);
    bf16_t* W2t   = (bf16_t*)(ws + W2T_OFF);
    bf16_t* nW1t  = (bf16_t*)(ws + NW1T_OFF);
    bf16_t* nW2t  = (bf16_t*)(ws + NW2T_OFF);
    float*  biasF = (float*)(ws + BIASF_OFF);
    bf16_t* xb    = (bf16_t*)(ws + XB_OFF);
    bf16_t* agg   = (bf16_t*)(ws + AGG_OFF);

    detect_kernel<<<1, 1, 0, stream>>>((const unsigned short*)x,
                                       (const unsigned int*)ei, flags);

    prep_kernel<bf16_t><<<403, 256, 0, stream>>>(
        (const bf16_t*)eW1, (const bf16_t*)eW2, (const bf16_t*)nW1, (const bf16_t*)nW2,
        (const bf16_t*)eb1, (const bf16_t*)eb2, (const bf16_t*)nb1, (const bf16_t*)nb2,
        W1t, W2t, nW1t, nW2t, biasF, flags);
    prep_kernel<float><<<403, 256, 0, stream>>>(
        (const float*)eW1, (const float*)eW2, (const float*)nW1, (const float*)nW2,
        (const float*)eb1, (const float*)eb2, (const float*)nb1, (const float*)nb2,
        W1t, W2t, nW1t, nW2t, biasF, flags);

    if (ws_size >= WS_NEED) {
        // ---- optimized path: bf16 gather copy + pk-bf16 agg in ws ----
        (void)hipMemsetAsync(agg, 0, AGG_BYTES, stream);
        conv_x_kernel<bf16_t><<<3125, 256, 0, stream>>>((const bf16_t*)x, xb, flags);
        conv_x_kernel<float><<<3125, 256, 0, stream>>>((const float*)x, xb, flags);

        edge_kernel_v2<<<EE / 64, 256, 0, stream>>>(xb, ei, ea, W1t, W2t, biasF, agg, flags);

        node_kernel_v2<bf16_t><<<(NN + 63) / 64, 256, 0, stream>>>(
            (const bf16_t*)x, xb, agg, nW1t, nW2t, biasF, (bf16_t*)d_out, flags);
        node_kernel_v2<float><<<(NN + 63) / 64, 256, 0, stream>>>(
            (const float*)x, xb, agg, nW1t, nW2t, biasF, (float*)d_out, flags);
    } else {
        // ---- legacy fallback (round-4 proven): agg aliased into d_out ----
        zero_kernel<bf16_t><<<6250, 256, 0, stream>>>((float4*)d_out, flags);
        zero_kernel<float><<<6250, 256, 0, stream>>>((float4*)d_out, flags);

        edge_kernel_legacy<bf16_t><<<EE / 64, 256, 0, stream>>>(
            (const bf16_t*)x, ei, (const bf16_t*)ea, W1t, (const bf16_t*)eb1,
            W2t, (const bf16_t*)eb2, d_out, flags);
        edge_kernel_legacy<float><<<EE / 64, 256, 0, stream>>>(
            (const float*)x, ei, (const float*)ea, W1t, (const float*)eb1,
            W2t, (const float*)eb2, d_out, flags);

        node_kernel_legacy<bf16_t><<<(NN + 63) / 64, 256, 0, stream>>>(
            (const bf16_t*)x, nW1t, (const bf16_t*)nb1, nW2t, (const bf16_t*)nb2,
            d_out, flags);
        node_kernel_legacy<float><<<(NN + 63) / 64, 256, 0, stream>>>(
            (const float*)x, nW1t, (const float*)nb1, nW2t, (const float*)nb2,
            d_out, flags);
    }
}

// Round 6
// 555.857 us; speedup vs baseline: 1.1229x; 1.0881x over previous
//
#include <hip/hip_runtime.h>
#include <hip/hip_bf16.h>
#include <type_traits>

typedef __bf16 bf16_t;
typedef __bf16 bf16x8 __attribute__((ext_vector_type(8)));
typedef float floatx4 __attribute__((ext_vector_type(4)));
typedef short v2s __attribute__((ext_vector_type(2)));

#define NN 50000
#define EE 800000
#define DD 128

// ---- ws layout (bytes) ----
#define W1T_OFF   256                                  // [128][288] (K 272->288 zero-pad)
#define W2T_OFF   (W1T_OFF + (size_t)128 * 288 * 2)    // [128][128]
#define NW1T_OFF  (W2T_OFF + (size_t)128 * 128 * 2)    // [128][256]
#define NW2T_OFF  (NW1T_OFF + (size_t)128 * 256 * 2)   // [128][128]
#define BIASF_OFF (NW2T_OFF + (size_t)128 * 128 * 2)   // float[512]: b1|b2|nb1|nb2
#define XB_OFF    207360                               // bf16 x copy [NN][DD]
#define AGG_OFF   (XB_OFF + (size_t)NN * DD * 2)       // bf16 agg [NN][DD]
#define AGG_BYTES ((size_t)NN * DD * 2)
#define WS_V2     (AGG_OFF + AGG_BYTES)                // 25,807,360 (proven available)
#define P_OFF     WS_V2                                // bf16 P = x @ eW1[0:128]
#define Q_OFF     (P_OFF + (size_t)NN * DD * 2)        // bf16 Q = x @ eW1[128:256]
#define WS_V3     (Q_OFF + (size_t)NN * DD * 2)        // 51,407,360

// LDS pitches (bf16 elems)
#define PA 304   // v2 edge A pitch
#define PB 48    // B chunk pitch (32 + 16 pad)
#define PN 272   // node A pitch (256 + 16 pad)
#define PH 136   // v3 h/x pitch (128 + 8 pad; 272B rows, 16B-aligned)

// ---- dtype-detect ----
__global__ void detect_kernel(const unsigned short* __restrict__ xraw,
                              const unsigned int* __restrict__ eiraw,
                              int* __restrict__ flags)
{
    int cnt = 0;
    for (int i = 0; i < 64; ++i) {
        unsigned short u = xraw[2 * i];
        int ex = (u >> 7) & 0xFF;
        if (ex >= 100 && ex <= 140) cnt++;
    }
    flags[0] = (cnt < 32) ? 1 : 0;   // 1 => fp32
    int zc = 0;
    for (int i = 0; i < 32; ++i)
        if (eiraw[2 * i + 1] == 0u) zc++;
    flags[1] = (zc >= 16) ? 1 : 0;   // 1 => int64
}

__device__ inline int load_idx(const void* ei, int i64, size_t pos)
{
    return i64 ? (int)((const long long*)ei)[pos] : ((const int*)ei)[pos];
}

template <typename FT>
__device__ inline void cp32(bf16_t* dst, const FT* src)
{
    if constexpr (std::is_same<FT, float>::value) {
#pragma unroll
        for (int i = 0; i < 32; i += 4) {
            float4 v = *(const float4*)(src + i);
            dst[i + 0] = (bf16_t)v.x; dst[i + 1] = (bf16_t)v.y;
            dst[i + 2] = (bf16_t)v.z; dst[i + 3] = (bf16_t)v.w;
        }
    } else {
#pragma unroll
        for (int i = 0; i < 32; i += 8)
            *(bf16x8*)(dst + i) = *(const bf16x8*)(src + i);
    }
}

template <typename FT>
__device__ inline void cp8(bf16_t* dst, const FT* src)
{
    if constexpr (std::is_same<FT, float>::value) {
#pragma unroll
        for (int i = 0; i < 8; i += 4) {
            float4 v = *(const float4*)(src + i);
            dst[i + 0] = (bf16_t)v.x; dst[i + 1] = (bf16_t)v.y;
            dst[i + 2] = (bf16_t)v.z; dst[i + 3] = (bf16_t)v.w;
        }
    } else {
        *(bf16x8*)dst = *(const bf16x8*)src;
    }
}

__device__ inline void pk_atomic_add_bf16(bf16_t* addr, float lo, float hi)
{
#if __has_builtin(__builtin_amdgcn_global_atomic_fadd_v2bf16)
    union { bf16_t b[2]; v2s s; } pk;
    pk.b[0] = (bf16_t)lo;
    pk.b[1] = (bf16_t)hi;
    (void)__builtin_amdgcn_global_atomic_fadd_v2bf16((v2s*)addr, pk.s);
#else
    unsigned int* w = (unsigned int*)addr;
    unsigned int old = __hip_atomic_load(w, __ATOMIC_RELAXED, __HIP_MEMORY_SCOPE_AGENT);
    while (true) {
        union { unsigned int u; bf16_t b[2]; } cur;
        cur.u = old;
        cur.b[0] = (bf16_t)((float)cur.b[0] + lo);
        cur.b[1] = (bf16_t)((float)cur.b[1] + hi);
        unsigned int prev = atomicCAS(w, old, cur.u);
        if (prev == old) break;
        old = prev;
    }
#endif
}

// ---- prep: transpose weights -> bf16 ws; biases -> float ws ----
template <typename FT>
__global__ __launch_bounds__(256) void prep_kernel(
    const FT* __restrict__ eW1, const FT* __restrict__ eW2,
    const FT* __restrict__ nW1, const FT* __restrict__ nW2,
    const FT* __restrict__ b1, const FT* __restrict__ b2,
    const FT* __restrict__ nb1, const FT* __restrict__ nb2,
    bf16_t* __restrict__ W1t, bf16_t* __restrict__ W2t,
    bf16_t* __restrict__ nW1t, bf16_t* __restrict__ nW2t,
    float* __restrict__ biasF, const int* __restrict__ flags)
{
    constexpr int WANT = std::is_same<FT, float>::value ? 1 : 0;
    if (flags[0] != WANT) return;
    int idx = blockIdx.x * 256 + threadIdx.x;
    if (idx < 128 * 288) {
        int n = idx / 288;
        int k = idx - n * 288;
        W1t[idx] = (k < 272) ? (bf16_t)(float)eW1[k * 128 + n] : (bf16_t)0.0f;
    } else if (idx < 128 * 288 + 128 * 128) {
        int j = idx - 128 * 288;
        int n = j >> 7, k = j & 127;
        W2t[j] = (bf16_t)(float)eW2[k * 128 + n];
    } else if (idx < 128 * 288 + 128 * 128 + 128 * 256) {
        int j = idx - (128 * 288 + 128 * 128);
        int n = j >> 8, k = j & 255;
        nW1t[j] = (bf16_t)(float)nW1[k * 128 + n];
    } else if (idx < 102400) {
        int j = idx - (128 * 288 + 128 * 128 + 128 * 256);
        int n = j >> 7, k = j & 127;
        nW2t[j] = (bf16_t)(float)nW2[k * 128 + n];
    } else if (idx < 102912) {
        int j = idx - 102400;
        int which = j >> 7, c = j & 127;
        const FT* src = which == 0 ? b1 : which == 1 ? b2 : which == 2 ? nb1 : nb2;
        biasF[j] = (float)src[c];
    }
}

// ---- conv_x: x (FT) -> xb (bf16) ----
template <typename FT>
__global__ __launch_bounds__(256) void conv_x_kernel(
    const FT* __restrict__ x, bf16_t* __restrict__ xb,
    const int* __restrict__ flags)
{
    constexpr int WANT = std::is_same<FT, float>::value ? 1 : 0;
    if (flags[0] != WANT) return;
    size_t i = ((size_t)blockIdx.x * 256 + threadIdx.x) * 8;
    if (i >= (size_t)NN * DD) return;
    bf16x8 v;
    if constexpr (std::is_same<FT, float>::value) {
        float4 a = *(const float4*)(x + i);
        float4 b = *(const float4*)(x + i + 4);
        v[0] = (bf16_t)a.x; v[1] = (bf16_t)a.y; v[2] = (bf16_t)a.z; v[3] = (bf16_t)a.w;
        v[4] = (bf16_t)b.x; v[5] = (bf16_t)b.y; v[6] = (bf16_t)b.z; v[7] = (bf16_t)b.w;
    } else {
        v = *(const bf16x8*)(x + i);
    }
    *(bf16x8*)(xb + i) = v;
}

// ---- pq: P = xb @ eW1[0:128], Q = xb @ eW1[128:256] (both bf16 to ws) ----
__global__ __launch_bounds__(256) void pq_kernel(
    const bf16_t* __restrict__ xb, const bf16_t* __restrict__ W1t,
    bf16_t* __restrict__ P, bf16_t* __restrict__ Q)
{
    __shared__ bf16_t sX[64 * PH];
    __shared__ bf16_t sB[128 * PB];
    const int tid = threadIdx.x;
    const int n0 = blockIdx.x * 64;

    {
        const int m = tid >> 2;
        const int part = tid & 3;
        int n = n0 + m;
        if (n >= NN) n = NN - 1;
        const bf16x8* src = (const bf16x8*)(xb + (size_t)n * DD + part * 32);
        bf16x8* dst = (bf16x8*)&sX[m * PH + part * 32];
#pragma unroll
        for (int i = 0; i < 4; ++i) dst[i] = src[i];
    }

    const int lane = tid & 63;
    const int wv = tid >> 6;
    const int ml = lane & 15;
    const int q = lane >> 4;
    const int m0 = wv * 16;
    const floatx4 fzero = {0.f, 0.f, 0.f, 0.f};

    for (int pass = 0; pass < 2; ++pass) {
        floatx4 acc[8];
#pragma unroll
        for (int i = 0; i < 8; ++i) acc[i] = fzero;

        for (int kc = 0; kc < 4; ++kc) {
            __syncthreads();
            {
                const int n = tid >> 1;
                const int half = tid & 1;
                const bf16x8* src = (const bf16x8*)(W1t + n * 288 + pass * 128 + kc * 32 + half * 16);
                bf16x8* dst = (bf16x8*)&sB[n * PB + half * 16];
                dst[0] = src[0];
                dst[1] = src[1];
            }
            __syncthreads();
            const bf16x8 a = *(const bf16x8*)&sX[(m0 + ml) * PH + kc * 32 + q * 8];
#pragma unroll
            for (int nt = 0; nt < 8; ++nt) {
                const bf16x8 b = *(const bf16x8*)&sB[(nt * 16 + ml) * PB + q * 8];
                acc[nt] = __builtin_amdgcn_mfma_f32_16x16x32_bf16(a, b, acc[nt], 0, 0, 0);
            }
        }

        bf16_t* dst = pass ? Q : P;
#pragma unroll
        for (int r = 0; r < 4; ++r) {
            const int n = n0 + m0 + q * 4 + r;
#pragma unroll
            for (int nt = 0; nt < 8; ++nt) {
                float v = acc[nt][r];
                const float pv = __shfl_xor(v, 1, 64);
                if (((lane & 1) == 0) && n < NN) {
                    union { bf16_t b[2]; unsigned int u; } pk;
                    pk.b[0] = (bf16_t)v;
                    pk.b[1] = (bf16_t)pv;
                    *(unsigned int*)(dst + (size_t)n * DD + nt * 16 + ml) = pk.u;
                }
            }
        }
    }
}

// ======== edge v3: h = silu(P[row]+Q[col]+ea@W1ea+b1); m=silu(h@W2+b2); scatter ========
__global__ __launch_bounds__(256) void edge_kernel_v3(
    const void* __restrict__ ei, const void* __restrict__ ea,
    const bf16_t* __restrict__ P, const bf16_t* __restrict__ Q,
    const bf16_t* __restrict__ W1t, const bf16_t* __restrict__ W2t,
    const float* __restrict__ biasF,
    bf16_t* __restrict__ agg, const int* __restrict__ flags)
{
    const int f32 = flags[0];
    const int i64 = flags[1];

    __shared__ bf16_t sH[64 * PH];    // P+Q sum, then h (layer-2 A operand)
    __shared__ bf16_t sEA[64 * 32];   // ea tile, k 16..31 zero
    __shared__ bf16_t sB[128 * PB];   // B staging: ea-chunk of W1t, then W2 chunks
    const int tid = threadIdx.x;
    const int e0 = blockIdx.x * 64;

    // ---- stage: sH = bf16(P[row]+Q[col]); sEA; sB = W1t k-chunk 8 (ea cols) ----
    {
        const int m = tid >> 2;
        const int part = tid & 3;
        const int e = e0 + m;
        int rn = load_idx(ei, i64, e);
        int cn = load_idx(ei, i64, (size_t)EE + e);
        rn = min(max(rn, 0), NN - 1);
        cn = min(max(cn, 0), NN - 1);
        const bf16x8* pr = (const bf16x8*)(P + (size_t)rn * DD + part * 32);
        const bf16x8* qc = (const bf16x8*)(Q + (size_t)cn * DD + part * 32);
#pragma unroll
        for (int i = 0; i < 4; ++i) {
            bf16x8 a = pr[i], b = qc[i], o;
#pragma unroll
            for (int j = 0; j < 8; ++j) o[j] = (bf16_t)((float)a[j] + (float)b[j]);
            *(bf16x8*)&sH[m * PH + part * 32 + i * 8] = o;
        }
        if (part < 2) {
            if (f32) cp8<float>(&sEA[m * 32 + part * 8], (const float*)ea + (size_t)e * 16 + part * 8);
            else     cp8<bf16_t>(&sEA[m * 32 + part * 8], (const bf16_t*)ea + (size_t)e * 16 + part * 8);
        } else {
            *(float4*)&sEA[m * 32 + part * 8] = make_float4(0.f, 0.f, 0.f, 0.f);
        }
        {
            const int n = tid >> 1;
            const int half = tid & 1;
            const bf16x8* src = (const bf16x8*)(W1t + n * 288 + 256 + half * 16);
            bf16x8* dst = (bf16x8*)&sB[n * PB + half * 16];
            dst[0] = src[0];
            dst[1] = src[1];
        }
    }
    __syncthreads();

    const int lane = tid & 63;
    const int wv = tid >> 6;
    const int ml = lane & 15;
    const int q = lane >> 4;
    const int m0 = wv * 16;
    const floatx4 fzero = {0.f, 0.f, 0.f, 0.f};

    // ---- ea contribution: one K=32 MFMA chunk ----
    floatx4 acc[8];
#pragma unroll
    for (int i = 0; i < 8; ++i) acc[i] = fzero;
    {
        const bf16x8 a = *(const bf16x8*)&sEA[(m0 + ml) * 32 + q * 8];
#pragma unroll
        for (int nt = 0; nt < 8; ++nt) {
            const bf16x8 b = *(const bf16x8*)&sB[(nt * 16 + ml) * PB + q * 8];
            acc[nt] = __builtin_amdgcn_mfma_f32_16x16x32_bf16(a, b, acc[nt], 0, 0, 0);
        }
    }

    // ---- h = silu(acc + (P+Q) + b1), written back into sH (same cell, same lane) ----
#pragma unroll
    for (int nt = 0; nt < 8; ++nt) {
        const float bias = biasF[nt * 16 + ml];
#pragma unroll
        for (int r = 0; r < 4; ++r) {
            const int row = m0 + q * 4 + r;
            const int col = nt * 16 + ml;
            float v = acc[nt][r] + bias + (float)sH[row * PH + col];
            v = v / (1.f + __expf(-v));
            sH[row * PH + col] = (bf16_t)v;
        }
    }

    floatx4 acc2[8];
#pragma unroll
    for (int i = 0; i < 8; ++i) acc2[i] = fzero;

    // ---- layer 2: [64x128] @ [128x128], 4 K-chunks ----
    for (int kc = 0; kc < 4; ++kc) {
        __syncthreads();
        {
            const int n = tid >> 1;
            const int half = tid & 1;
            const bf16x8* src = (const bf16x8*)(W2t + n * 128 + kc * 32 + half * 16);
            bf16x8* dst = (bf16x8*)&sB[n * PB + half * 16];
            dst[0] = src[0];
            dst[1] = src[1];
        }
        __syncthreads();
        const bf16x8 a = *(const bf16x8*)&sH[(m0 + ml) * PH + kc * 32 + q * 8];
#pragma unroll
        for (int nt = 0; nt < 8; ++nt) {
            const bf16x8 b = *(const bf16x8*)&sB[(nt * 16 + ml) * PB + q * 8];
            acc2[nt] = __builtin_amdgcn_mfma_f32_16x16x32_bf16(a, b, acc2[nt], 0, 0, 0);
        }
    }

    // ---- m_ij = silu(acc2 + b2); pk-bf16 scatter-add ----
    float bias2[8];
#pragma unroll
    for (int nt = 0; nt < 8; ++nt) bias2[nt] = biasF[128 + nt * 16 + ml];
#pragma unroll
    for (int r = 0; r < 4; ++r) {
        const int e = e0 + m0 + q * 4 + r;
        int rn = load_idx(ei, i64, e);
        rn = min(max(rn, 0), NN - 1);
#pragma unroll
        for (int nt = 0; nt < 8; ++nt) {
            float v = acc2[nt][r] + bias2[nt];
            v = v / (1.f + __expf(-v));
            const float pv = __shfl_xor(v, 1, 64);
            if ((ml & 1) == 0)
                pk_atomic_add_bf16(agg + (size_t)rn * DD + nt * 16 + ml, v, pv);
        }
    }
}

// ======== edge v2 (fallback if ws too small for P/Q) ========
__global__ __launch_bounds__(256) void edge_kernel_v2(
    const bf16_t* __restrict__ xb, const void* __restrict__ ei,
    const void* __restrict__ ea,
    const bf16_t* __restrict__ W1t, const bf16_t* __restrict__ W2t,
    const float* __restrict__ biasF,
    bf16_t* __restrict__ agg, const int* __restrict__ flags)
{
    const int f32 = flags[0];
    const int i64 = flags[1];

    __shared__ bf16_t sA[64 * PA];
    __shared__ bf16_t sB[128 * PB];
    const int tid = threadIdx.x;
    const int e0 = blockIdx.x * 64;

    {
        const int m = tid >> 2;
        const int part = tid & 3;
        const int e = e0 + m;
        int rn = load_idx(ei, i64, e);
        int cn = load_idx(ei, i64, (size_t)EE + e);
        rn = min(max(rn, 0), NN - 1);
        cn = min(max(cn, 0), NN - 1);
        const bf16x8* xr = (const bf16x8*)(xb + (size_t)rn * DD + part * 32);
        const bf16x8* xc = (const bf16x8*)(xb + (size_t)cn * DD + part * 32);
        bf16x8* dR = (bf16x8*)&sA[m * PA + part * 32];
        bf16x8* dC = (bf16x8*)&sA[m * PA + 128 + part * 32];
#pragma unroll
        for (int i = 0; i < 4; ++i) dR[i] = xr[i];
#pragma unroll
        for (int i = 0; i < 4; ++i) dC[i] = xc[i];
        if (part < 2) {
            if (f32) cp8<float>(&sA[m * PA + 256 + part * 8], (const float*)ea + (size_t)e * 16 + part * 8);
            else     cp8<bf16_t>(&sA[m * PA + 256 + part * 8], (const bf16_t*)ea + (size_t)e * 16 + part * 8);
        } else {
            *(float4*)&sA[m * PA + 256 + part * 8] = make_float4(0.f, 0.f, 0.f, 0.f);
        }
    }

    const int lane = tid & 63;
    const int wv = tid >> 6;
    const int ml = lane & 15;
    const int q = lane >> 4;
    const int m0 = wv * 16;

    const floatx4 fzero = {0.f, 0.f, 0.f, 0.f};
    floatx4 acc[8];
#pragma unroll
    for (int i = 0; i < 8; ++i) acc[i] = fzero;

    for (int kc = 0; kc < 9; ++kc) {
        __syncthreads();
        {
            const int n = tid >> 1;
            const int half = tid & 1;
            const bf16x8* src = (const bf16x8*)(W1t + n * 288 + kc * 32 + half * 16);
            bf16x8* dst = (bf16x8*)&sB[n * PB + half * 16];
            dst[0] = src[0];
            dst[1] = src[1];
        }
        __syncthreads();
        const bf16x8 a = *(const bf16x8*)&sA[(m0 + ml) * PA + kc * 32 + q * 8];
#pragma unroll
        for (int nt = 0; nt < 8; ++nt) {
            const bf16x8 b = *(const bf16x8*)&sB[(nt * 16 + ml) * PB + q * 8];
            acc[nt] = __builtin_amdgcn_mfma_f32_16x16x32_bf16(a, b, acc[nt], 0, 0, 0);
        }
    }

#pragma unroll
    for (int nt = 0; nt < 8; ++nt) {
        const float bias = biasF[nt * 16 + ml];
#pragma unroll
        for (int r = 0; r < 4; ++r) {
            float v = acc[nt][r] + bias;
            v = v / (1.f + __expf(-v));
            sA[(m0 + q * 4 + r) * PA + nt * 16 + ml] = (bf16_t)v;
        }
    }
    __syncthreads();

    floatx4 acc2[8];
#pragma unroll
    for (int i = 0; i < 8; ++i) acc2[i] = fzero;

    for (int kc = 0; kc < 4; ++kc) {
        __syncthreads();
        {
            const int n = tid >> 1;
            const int half = tid & 1;
            const bf16x8* src = (const bf16x8*)(W2t + n * 128 + kc * 32 + half * 16);
            bf16x8* dst = (bf16x8*)&sB[n * PB + half * 16];
            dst[0] = src[0];
            dst[1] = src[1];
        }
        __syncthreads();
        const bf16x8 a = *(const bf16x8*)&sA[(m0 + ml) * PA + kc * 32 + q * 8];
#pragma unroll
        for (int nt = 0; nt < 8; ++nt) {
            const bf16x8 b = *(const bf16x8*)&sB[(nt * 16 + ml) * PB + q * 8];
            acc2[nt] = __builtin_amdgcn_mfma_f32_16x16x32_bf16(a, b, acc2[nt], 0, 0, 0);
        }
    }

    float bias2[8];
#pragma unroll
    for (int nt = 0; nt < 8; ++nt) bias2[nt] = biasF[128 + nt * 16 + ml];
#pragma unroll
    for (int r = 0; r < 4; ++r) {
        const int e = e0 + m0 + q * 4 + r;
        int rn = load_idx(ei, i64, e);
        rn = min(max(rn, 0), NN - 1);
#pragma unroll
        for (int nt = 0; nt < 8; ++nt) {
            float v = acc2[nt][r] + bias2[nt];
            v = v / (1.f + __expf(-v));
            const float pv = __shfl_xor(v, 1, 64);
            if ((ml & 1) == 0)
                pk_atomic_add_bf16(agg + (size_t)rn * DD + nt * 16 + ml, v, pv);
        }
    }
}

// -------- node MLP: out = x + (silu([xb|agg] @ nW1 + nb1) @ nW2 + nb2) --------
template <typename FT>
__global__ __launch_bounds__(256) void node_kernel_v2(
    const FT* __restrict__ x, const bf16_t* __restrict__ xb,
    const bf16_t* __restrict__ agg,
    const bf16_t* __restrict__ nW1t, const bf16_t* __restrict__ nW2t,
    const float* __restrict__ biasF,
    FT* __restrict__ out, const int* __restrict__ flags)
{
    constexpr int WANT = std::is_same<FT, float>::value ? 1 : 0;
    if (flags[0] != WANT) return;

    __shared__ bf16_t sA[64 * PN];
    __shared__ bf16_t sB[128 * PB];
    const int tid = threadIdx.x;
    const int n0 = blockIdx.x * 64;

    {
        const int m = tid >> 2;
        const int p = tid & 3;
        int n = n0 + m;
        if (n >= NN) n = NN - 1;
        const bf16_t* srcbase = (p < 2) ? xb : agg;
        const int col = (p & 1) * 64;
        const bf16x8* src = (const bf16x8*)(srcbase + (size_t)n * DD + col);
        bf16x8* dst = (bf16x8*)&sA[m * PN + (p >> 1) * 128 + col];
#pragma unroll
        for (int i = 0; i < 8; ++i) dst[i] = src[i];
    }

    const int lane = tid & 63;
    const int wv = tid >> 6;
    const int ml = lane & 15;
    const int q = lane >> 4;
    const int m0 = wv * 16;

    const floatx4 fzero = {0.f, 0.f, 0.f, 0.f};
    floatx4 acc[8];
#pragma unroll
    for (int i = 0; i < 8; ++i) acc[i] = fzero;

    for (int kc = 0; kc < 8; ++kc) {
        __syncthreads();
        {
            const int n = tid >> 1;
            const int half = tid & 1;
            const bf16x8* src = (const bf16x8*)(nW1t + n * 256 + kc * 32 + half * 16);
            bf16x8* dst = (bf16x8*)&sB[n * PB + half * 16];
            dst[0] = src[0];
            dst[1] = src[1];
        }
        __syncthreads();
        const bf16x8 a = *(const bf16x8*)&sA[(m0 + ml) * PN + kc * 32 + q * 8];
#pragma unroll
        for (int nt = 0; nt < 8; ++nt) {
            const bf16x8 b = *(const bf16x8*)&sB[(nt * 16 + ml) * PB + q * 8];
            acc[nt] = __builtin_amdgcn_mfma_f32_16x16x32_bf16(a, b, acc[nt], 0, 0, 0);
        }
    }

#pragma unroll
    for (int nt = 0; nt < 8; ++nt) {
        const float bias = biasF[256 + nt * 16 + ml];
#pragma unroll
        for (int r = 0; r < 4; ++r) {
            float v = acc[nt][r] + bias;
            v = v / (1.f + __expf(-v));
            sA[(m0 + q * 4 + r) * PN + nt * 16 + ml] = (bf16_t)v;
        }
    }
    __syncthreads();

    floatx4 acc2[8];
#pragma unroll
    for (int i = 0; i < 8; ++i) acc2[i] = fzero;

    for (int kc = 0; kc < 4; ++kc) {
        __syncthreads();
        {
            const int n = tid >> 1;
            const int half = tid & 1;
            const bf16x8* src = (const bf16x8*)(nW2t + n * 128 + kc * 32 + half * 16);
            bf16x8* dst = (bf16x8*)&sB[n * PB + half * 16];
            dst[0] = src[0];
            dst[1] = src[1];
        }
        __syncthreads();
        const bf16x8 a = *(const bf16x8*)&sA[(m0 + ml) * PN + kc * 32 + q * 8];
#pragma unroll
        for (int nt = 0; nt < 8; ++nt) {
            const bf16x8 b = *(const bf16x8*)&sB[(nt * 16 + ml) * PB + q * 8];
            acc2[nt] = __builtin_amdgcn_mfma_f32_16x16x32_bf16(a, b, acc2[nt], 0, 0, 0);
        }
    }

#pragma unroll
    for (int r = 0; r < 4; ++r) {
        const int n = n0 + m0 + q * 4 + r;
        if (n < NN) {
#pragma unroll
            for (int nt = 0; nt < 8; ++nt) {
                const int col = nt * 16 + ml;
                float v = acc2[nt][r] + biasF[384 + col];
                float xv = (float)x[(size_t)n * DD + col];
                out[(size_t)n * DD + col] = (FT)(xv + v);
            }
        }
    }
}

extern "C" void kernel_launch(void* const* d_in, const int* in_sizes, int n_in,
                              void* d_out, int out_size, void* d_ws, size_t ws_size,
                              hipStream_t stream)
{
    const void* x   = d_in[0];
    const void* ei  = d_in[1];
    const void* ea  = d_in[2];
    const void* eW1 = d_in[3];
    const void* eb1 = d_in[4];
    const void* eW2 = d_in[5];
    const void* eb2 = d_in[6];
    const void* nW1 = d_in[7];
    const void* nb1 = d_in[8];
    const void* nW2 = d_in[9];
    const void* nb2 = d_in[10];

    char* ws = (char*)d_ws;
    int*    flags = (int*)ws;
    bf16_t* W1t   = (bf16_t*)(ws + W1T_OFF);
    bf16_t* W2t   = (bf16_t*)(ws + W2T_OFF);
    bf16_t* nW1t  = (bf16_t*)(ws + NW1T_OFF);
    bf16_t* nW2t  = (bf16_t*)(ws + NW2T_OFF);
    float*  biasF = (float*)(ws + BIASF_OFF);
    bf16_t* xb    = (bf16_t*)(ws + XB_OFF);
    bf16_t* agg   = (bf16_t*)(ws + AGG_OFF);
    bf16_t* P     = (bf16_t*)(ws + P_OFF);
    bf16_t* Q     = (bf16_t*)(ws + Q_OFF);

    detect_kernel<<<1, 1, 0, stream>>>((const unsigned short*)x,
                                       (const unsigned int*)ei, flags);

    prep_kernel<bf16_t><<<403, 256, 0, stream>>>(
        (const bf16_t*)eW1, (const bf16_t*)eW2, (const bf16_t*)nW1, (const bf16_t*)nW2,
        (const bf16_t*)eb1, (const bf16_t*)eb2, (const bf16_t*)nb1, (const bf16_t*)nb2,
        W1t, W2t, nW1t, nW2t, biasF, flags);
    prep_kernel<float><<<403, 256, 0, stream>>>(
        (const float*)eW1, (const float*)eW2, (const float*)nW1, (const float*)nW2,
        (const float*)eb1, (const float*)eb2, (const float*)nb1, (const float*)nb2,
        W1t, W2t, nW1t, nW2t, biasF, flags);

    (void)hipMemsetAsync(agg, 0, AGG_BYTES, stream);
    conv_x_kernel<bf16_t><<<3125, 256, 0, stream>>>((const bf16_t*)x, xb, flags);
    conv_x_kernel<float><<<3125, 256, 0, stream>>>((const float*)x, xb, flags);

    if (ws_size >= WS_V3) {
        pq_kernel<<<(NN + 63) / 64, 256, 0, stream>>>(xb, W1t, P, Q);
        edge_kernel_v3<<<EE / 64, 256, 0, stream>>>(ei, ea, P, Q, W1t, W2t, biasF, agg, flags);
    } else {
        edge_kernel_v2<<<EE / 64, 256, 0, stream>>>(xb, ei, ea, W1t, W2t, biasF, agg, flags);
    }

    node_kernel_v2<bf16_t><<<(NN + 63) / 64, 256, 0, stream>>>(
        (const bf16_t*)x, xb, agg, nW1t, nW2t, biasF, (bf16_t*)d_out, flags);
    node_kernel_v2<float><<<(NN + 63) / 64, 256, 0, stream>>>(
        (const float*)x, xb, agg, nW1t, nW2t, biasF, (float*)d_out, flags);
}